// Round 4
// baseline (1849.792 us; speedup 1.0000x reference)
//
#include <hip/hip_runtime.h>
#include <stdint.h>
#include <stddef.h>

#define B_ 4
#define C_ 256
#define T_ 128
#define NB_ 64
#define NF_ 512
#define PLAT_ (T_*NB_)    // 8192
#define PSIDE_ (T_*NF_)   // 65536

using bf16x8 = __attribute__((ext_vector_type(8))) short;
using f32x4  = __attribute__((ext_vector_type(4))) float;

__device__ __forceinline__ float b2f(unsigned short h) {
  unsigned int u = ((unsigned int)h) << 16;
  return __builtin_bit_cast(float, u);
}
__device__ __forceinline__ unsigned short f2b(float f) {
  unsigned int u = __builtin_bit_cast(unsigned int, f);
  u += 0x7FFFu + ((u >> 16) & 1u);
  return (unsigned short)(u >> 16);
}

// 8-element loaders -> bf16x8 (external fp32 converts in-register)
__device__ __forceinline__ bf16x8 ld8(const unsigned short* p) {
  return *(const bf16x8*)p;
}
__device__ __forceinline__ bf16x8 ld8(const float* p) {
  float4 a = *(const float4*)p;
  float4 b = *(const float4*)(p + 4);
  bf16x8 r;
  r[0] = (short)f2b(a.x); r[1] = (short)f2b(a.y);
  r[2] = (short)f2b(a.z); r[3] = (short)f2b(a.w);
  r[4] = (short)f2b(b.x); r[5] = (short)f2b(b.y);
  r[6] = (short)f2b(b.z); r[7] = (short)f2b(b.w);
  return r;
}
__device__ __forceinline__ float ldv(float v) { return v; }
__device__ __forceinline__ float ldv(unsigned short v) { return b2f(v); }
__device__ __forceinline__ void stv(float* p, float v) { *p = v; }
__device__ __forceinline__ void stv(unsigned short* p, float v) { *p = f2b(v); }

enum { EPI_NONE = 0, EPI_SILU = 1, EPI_SKIP = 2, EPI_RESID = 3, EPI_SWIGLU = 4 };

// -------------------------------------------------------------------------
// RMS scale over channels of fp32 input: S[z*2^lpc + pl] =
//   rsqrt(mean_c X[z,c,Xoff+pl]^2 + 1e-6)
__global__ __launch_bounds__(256) void rms_k(const float* __restrict__ X,
                                             float* __restrict__ S,
                                             int Xs, int Xoff, int lpc)
{
  __shared__ float red[256];
  const int tid = threadIdx.x;
  const int pg = tid & 63, cg = tid >> 6;
  const unsigned int pix = blockIdx.x * 64u + pg;
  const unsigned int z = pix >> lpc;
  const unsigned int pl = pix & ((1u << lpc) - 1u);
  const float* Xb = X + (size_t)z * C_ * Xs + Xoff + pl;
  float s = 0.f;
  #pragma unroll 4
  for (int c = cg * 64; c < cg * 64 + 64; ++c) {
    float v = Xb[(size_t)c * Xs];
    s += v * v;
  }
  red[tid] = s;
  __syncthreads();
  if (cg == 0) {
    float tot = red[pg] + red[pg + 64] + red[pg + 128] + red[pg + 192];
    S[pix] = rsqrtf(tot * (1.0f / (float)C_) + 1e-6f);
  }
}

// fold per-channel norm weight into conv weight (fp32 in, bf16 out)
__global__ __launch_bounds__(256) void wprep_k(const float* __restrict__ w,
                                               const float* __restrict__ nw,
                                               unsigned short* __restrict__ out, int n)
{
  int i = blockIdx.x * 256 + threadIdx.x;
  if (i < n) out[i] = f2b(w[i] * nw[i & 255]);
}

// plain fp32 -> bf16 convert
__global__ __launch_bounds__(256) void cvt_k(const float* __restrict__ in,
                                             unsigned short* __restrict__ out, int n)
{
  int i = blockIdx.x * 256 + threadIdx.x;
  if (i < n) out[i] = f2b(in[i]);
}

// -------------------------------------------------------------------------
// GEMM: Y[z,m,Yoff+pl] = epi( colscale[z*Pc+pl] * sum_c W[m,c] X[z,c,Xoff+pl] + bias[m] )
// W is pre-converted bf16; X is fp32 (external) or bf16 (internal) via TX;
// Y is fp32 (d_out) or bf16 (internal) via TY. BM=64 BN=128 BK=32, 4 waves.
// EPI_SKIP/RESID read Yb[oidx] then write it (same thread/index — aliasing safe).
template<int EPI, typename TX, typename TY>
__global__ __launch_bounds__(256) void gemm_k(
    const TX* __restrict__ X,
    const unsigned short* __restrict__ W,
    const float* __restrict__ bias,
    const float* __restrict__ colscale,
    const float* __restrict__ sscale,
    TY* Y,
    int Xs, int Xoff, int Ys, int Yoff, int Pc)
{
  constexpr bool DUAL = (EPI == EPI_SWIGLU);
  __shared__ unsigned short sA[DUAL ? 2 : 1][64 * 40];
  __shared__ unsigned short sX[128 * 40];

  const int tid = threadIdx.x;
  const int lane = tid & 63;
  const int wid = tid >> 6;
  const int l15 = lane & 15;
  const int q4 = lane >> 4;
  const int z = blockIdx.z;
  const int p0 = blockIdx.x * 128;
  const int m0 = blockIdx.y * 64;
  const int mh = wid >> 1, nh = wid & 1;

  const TX* Xb = X + (size_t)z * C_ * Xs + Xoff;
  TY* Yb = Y + (size_t)z * C_ * Ys + Yoff;

  const f32x4 zf = {0.f, 0.f, 0.f, 0.f};
  f32x4 acc0[2][4];
  f32x4 acc1[2][4];
  #pragma unroll
  for (int i = 0; i < 2; ++i)
    #pragma unroll
    for (int j = 0; j < 4; ++j) { acc0[i][j] = zf; acc1[i][j] = zf; }

  const int arow = tid >> 2;
  const int acol = (tid & 3) << 3;
  const int xr = tid >> 4;
  const int xc = (tid & 15) << 3;

  for (int kt = 0; kt < 8; ++kt) {
    // stage weights 64x32 (bf16, direct)
    {
      bf16x8 a8 = ld8(W + (size_t)(m0 + arow) * C_ + kt * 32 + acol);
      *(bf16x8*)(&sA[0][arow * 40 + acol]) = a8;
      if constexpr (DUAL) {
        bf16x8 a8b = ld8(W + (size_t)(C_ + m0 + arow) * C_ + kt * 32 + acol);
        *(bf16x8*)(&sA[1][arow * 40 + acol]) = a8b;
      }
    }
    // stage X 32x128, transposed+swizzled (fp32 converts in-register)
    #pragma unroll
    for (int pass = 0; pass < 2; ++pass) {
      int r = xr + pass * 16;
      bf16x8 v8 = ld8(Xb + (size_t)(kt * 32 + r) * Xs + p0 + xc);
      int cb = r >> 3;
      #pragma unroll
      for (int j = 0; j < 8; ++j) {
        int n = xc + j;
        sX[n * 40 + ((cb ^ ((n >> 3) & 3)) << 3) + (r & 7)] = (unsigned short)v8[j];
      }
    }
    __syncthreads();

    bf16x8 af0[2], af1[2], bfr[4];
    #pragma unroll
    for (int mf = 0; mf < 2; ++mf) {
      int row = mh * 32 + mf * 16 + l15;
      af0[mf] = *(const bf16x8*)(&sA[0][row * 40 + q4 * 8]);
      if constexpr (DUAL) af1[mf] = *(const bf16x8*)(&sA[1][row * 40 + q4 * 8]);
    }
    #pragma unroll
    for (int nf = 0; nf < 4; ++nf) {
      int n = nh * 64 + nf * 16 + l15;
      bfr[nf] = *(const bf16x8*)(&sX[n * 40 + ((q4 ^ ((n >> 3) & 3)) << 3)]);
    }
    #pragma unroll
    for (int mf = 0; mf < 2; ++mf)
      #pragma unroll
      for (int nf = 0; nf < 4; ++nf) {
        acc0[mf][nf] = __builtin_amdgcn_mfma_f32_16x16x32_bf16(af0[mf], bfr[nf], acc0[mf][nf], 0, 0, 0);
        if constexpr (DUAL)
          acc1[mf][nf] = __builtin_amdgcn_mfma_f32_16x16x32_bf16(af1[mf], bfr[nf], acc1[mf][nf], 0, 0, 0);
      }
    __syncthreads();
  }

  // epilogue
  float qss = 0.f;
  if constexpr (EPI == EPI_SKIP) qss = sscale[0];
  float cs[4];
  #pragma unroll
  for (int nf = 0; nf < 4; ++nf) {
    int pl = p0 + nh * 64 + nf * 16 + l15;
    cs[nf] = colscale ? colscale[(size_t)z * Pc + pl] : 1.0f;
  }
  #pragma unroll
  for (int mf = 0; mf < 2; ++mf) {
    #pragma unroll
    for (int r = 0; r < 4; ++r) {
      int m = m0 + mh * 32 + mf * 16 + q4 * 4 + r;
      float b1 = bias[m];
      float b2v = 0.f;
      if constexpr (DUAL) b2v = bias[C_ + m];
      #pragma unroll
      for (int nf = 0; nf < 4; ++nf) {
        int pl = p0 + nh * 64 + nf * 16 + l15;
        size_t oidx = (size_t)m * Ys + pl;
        float y = acc0[mf][nf][r] * cs[nf] + b1;
        if constexpr (EPI == EPI_SILU) y = y / (1.0f + __expf(-y));
        if constexpr (EPI == EPI_SWIGLU) {
          float g = acc1[mf][nf][r] * cs[nf] + b2v;
          y = y * (g / (1.0f + __expf(-g)));
        }
        if constexpr (EPI == EPI_SKIP) y += qss * ldv(Yb[oidx]);
        if constexpr (EPI == EPI_RESID) y += ldv(Yb[oidx]);
        stv(&Yb[oidx], y);
      }
    }
  }
}

// -------------------------------------------------------------------------
// Fused cross-attention, one block per (z, t_local). All tensors bf16 except
// basis/scalars (fp32). Q/O layout [z][c][tl*NF+f] stride Qs; K/V global.
__global__ __launch_bounds__(256) void attn_k(
    const unsigned short* Q,
    const unsigned short* __restrict__ Kp,
    const unsigned short* __restrict__ Vp,
    const float* __restrict__ basis,
    const float* __restrict__ ssp,
    const float* __restrict__ psp,
    unsigned short* O,
    int Qs, int t0, int ltc)
{
  __shared__ unsigned short sK[64 * 264];   // [n][c] swizzled (B-operand)
  __shared__ unsigned short sV[256 * 72];   // [c][n] (A-operand)
  __shared__ unsigned short sQ[64 * 264];   // [f][c] swizzled (A-operand)
  __shared__ unsigned short sW[64 * 72];    // [f][n] softmax weights (B-operand)
  __shared__ unsigned short sB[64 * 72];    // [n][f] bias chunk

  const int tid = threadIdx.x;
  const int lane = tid & 63;
  const int wid = tid >> 6;
  const int l15 = lane & 15;
  const int q4 = lane >> 4;
  const int z = blockIdx.x >> ltc;
  const int tl = blockIdx.x & ((1 << ltc) - 1);

  const size_t qbase = (size_t)z * C_ * Qs + (size_t)tl * NF_;
  const size_t kbase = (size_t)z * C_ * PLAT_ + (size_t)(t0 + tl) * NB_;

  const float ss = ssp[0];
  const float ps = psp[0];
  const f32x4 zf = {0.f, 0.f, 0.f, 0.f};

  // stage K (transposed [n][c]) and V ([c][n]) once per block
  {
    const int c0 = tid >> 3;
    const int n0 = (tid & 7) << 3;
    #pragma unroll
    for (int pass = 0; pass < 8; ++pass) {
      int c = c0 + pass * 32;
      bf16x8 k8 = *(const bf16x8*)(Kp + kbase + (size_t)c * PLAT_ + n0);
      bf16x8 v8 = *(const bf16x8*)(Vp + kbase + (size_t)c * PLAT_ + n0);
      int cb = c >> 3;
      #pragma unroll
      for (int j = 0; j < 8; ++j) {
        int n = n0 + j;
        sK[n * 264 + ((cb ^ ((n >> 3) & 3)) << 3) + (c & 7)] = (unsigned short)k8[j];
      }
      *(bf16x8*)(&sV[c * 72 + n0]) = v8;
    }
  }

  for (int fc = 0; fc < 8; ++fc) {
    const int f0 = fc * 64;
    // stage Q chunk (transposed [f][c]) and fp32 bias chunk [n][f]
    {
      const int c0 = tid >> 3;
      const int fl0 = (tid & 7) << 3;
      #pragma unroll
      for (int pass = 0; pass < 8; ++pass) {
        int c = c0 + pass * 32;
        bf16x8 q8 = *(const bf16x8*)(Q + qbase + (size_t)c * Qs + f0 + fl0);
        int cb = c >> 3;
        #pragma unroll
        for (int j = 0; j < 8; ++j) {
          int f = fl0 + j;
          sQ[f * 264 + ((cb ^ ((f >> 3) & 3)) << 3) + (c & 7)] = (unsigned short)q8[j];
        }
      }
      const int nr = tid >> 3;
      #pragma unroll
      for (int pass = 0; pass < 2; ++pass) {
        int nn = nr + pass * 32;
        bf16x8 b8 = ld8(basis + (size_t)nn * NF_ + f0 + fl0);
        *(bf16x8*)(&sB[nn * 72 + fl0]) = b8;
      }
    }
    __syncthreads();

    // scores: wave wid owns f rows [wid*16, wid*16+16)
    f32x4 sacc[4];
    #pragma unroll
    for (int nt = 0; nt < 4; ++nt) sacc[nt] = zf;
    #pragma unroll
    for (int kt = 0; kt < 8; ++kt) {
      int frow = wid * 16 + l15;
      int kb = kt * 4 + q4;
      bf16x8 a8 = *(const bf16x8*)(&sQ[frow * 264 + ((kb ^ ((frow >> 3) & 3)) << 3)]);
      #pragma unroll
      for (int nt = 0; nt < 4; ++nt) {
        int n = nt * 16 + l15;
        bf16x8 b8 = *(const bf16x8*)(&sK[n * 264 + ((kb ^ ((n >> 3) & 3)) << 3)]);
        sacc[nt] = __builtin_amdgcn_mfma_f32_16x16x32_bf16(a8, b8, sacc[nt], 0, 0, 0);
      }
    }

    // softmax over n=64
    #pragma unroll
    for (int r = 0; r < 4; ++r) {
      const int fcl = wid * 16 + q4 * 4 + r;
      float v[4];
      #pragma unroll
      for (int nt = 0; nt < 4; ++nt)
        v[nt] = sacc[nt][r] * ss + b2f(sB[(nt * 16 + l15) * 72 + fcl]) * ps;
      float mx = fmaxf(fmaxf(v[0], v[1]), fmaxf(v[2], v[3]));
      #pragma unroll
      for (int d = 1; d < 16; d <<= 1) mx = fmaxf(mx, __shfl_xor(mx, d));
      float e[4], sum = 0.f;
      #pragma unroll
      for (int nt = 0; nt < 4; ++nt) { e[nt] = __expf(v[nt] - mx); sum += e[nt]; }
      #pragma unroll
      for (int d = 1; d < 16; d <<= 1) sum += __shfl_xor(sum, d);
      float inv = 1.0f / sum;
      #pragma unroll
      for (int nt = 0; nt < 4; ++nt)
        sW[fcl * 72 + nt * 16 + l15] = f2b(e[nt] * inv);
    }
    __syncthreads();

    // PV: wave wid owns c rows [wid*64, wid*64+64)
    f32x4 pacc[4][4];
    #pragma unroll
    for (int mf = 0; mf < 4; ++mf)
      #pragma unroll
      for (int nf = 0; nf < 4; ++nf) pacc[mf][nf] = zf;
    #pragma unroll
    for (int kt = 0; kt < 2; ++kt) {
      int k0 = kt * 32 + q4 * 8;
      bf16x8 a8[4], b8[4];
      #pragma unroll
      for (int mf = 0; mf < 4; ++mf)
        a8[mf] = *(const bf16x8*)(&sV[(wid * 64 + mf * 16 + l15) * 72 + k0]);
      #pragma unroll
      for (int nf = 0; nf < 4; ++nf)
        b8[nf] = *(const bf16x8*)(&sW[(nf * 16 + l15) * 72 + k0]);
      #pragma unroll
      for (int mf = 0; mf < 4; ++mf)
        #pragma unroll
        for (int nf = 0; nf < 4; ++nf)
          pacc[mf][nf] = __builtin_amdgcn_mfma_f32_16x16x32_bf16(a8[mf], b8[nf], pacc[mf][nf], 0, 0, 0);
    }
    #pragma unroll
    for (int mf = 0; mf < 4; ++mf)
      #pragma unroll
      for (int r = 0; r < 4; ++r) {
        int c = wid * 64 + mf * 16 + q4 * 4 + r;
        #pragma unroll
        for (int nf = 0; nf < 4; ++nf) {
          int f = f0 + nf * 16 + l15;
          O[qbase + (size_t)c * Qs + f] = f2b(pacc[mf][nf][r]);
        }
      }
    __syncthreads();
  }
}

// -------------------------------------------------------------------------
extern "C" void kernel_launch(void* const* d_in, const int* in_sizes, int n_in,
                              void* d_out, int out_size, void* d_ws, size_t ws_size,
                              hipStream_t stream)
{
  (void)in_sizes; (void)n_in; (void)out_size;
  const float* latent     = (const float*)d_in[0];
  const float* side       = (const float*)d_in[1];
  const float* basis      = (const float*)d_in[2];
  const float* lp_norm_w  = (const float*)d_in[3];
  const float* lp_w       = (const float*)d_in[4];
  const float* lp_b       = (const float*)d_in[5];
  const float* qn_w       = (const float*)d_in[6];
  const float* qmlp_in_w  = (const float*)d_in[7];
  const float* qmlp_in_b  = (const float*)d_in[8];
  const float* qmlp_out_w = (const float*)d_in[9];
  const float* qmlp_out_b = (const float*)d_in[10];
  const float* q_w        = (const float*)d_in[11];
  const float* q_b        = (const float*)d_in[12];
  const float* k_w        = (const float*)d_in[13];
  const float* k_b        = (const float*)d_in[14];
  const float* v_w        = (const float*)d_in[15];
  const float* v_b        = (const float*)d_in[16];
  const float* o_w        = (const float*)d_in[17];
  const float* o_b        = (const float*)d_in[18];
  const float* ffn_norm_w = (const float*)d_in[19];
  const float* ffn_in_w   = (const float*)d_in[20];
  const float* ffn_in_b   = (const float*)d_in[21];
  const float* ffn_out_w  = (const float*)d_in[22];
  const float* ffn_out_b  = (const float*)d_in[23];
  const float* sc_scale   = (const float*)d_in[24];
  const float* pr_scale   = (const float*)d_in[25];
  const float* qk_scale   = (const float*)d_in[26];
  float* out = (float*)d_out;

  // ---- workspace carve, chunk count chosen to FIT ws_size ----
  auto align256 = [](size_t b) { return (b + 255) & ~(size_t)255; };
  const size_t wsmall = align256((size_t)C_ * C_ * 2);
  const size_t fixed_bytes =
      7 * wsmall + 2 * align256((size_t)2 * C_ * C_ * 2) +
      align256((size_t)B_ * PLAT_ * 4) + 3 * align256((size_t)B_ * C_ * PLAT_ * 2);
  int nc = 16;
  for (int c = 1; c <= 16; c <<= 1) {
    size_t Pcb = (size_t)PSIDE_ / c;
    size_t need = fixed_bytes + align256((size_t)B_ * Pcb * 4) + align256((size_t)B_ * C_ * Pcb * 2);
    if (need <= ws_size) { nc = c; break; }
  }
  const int Pc  = PSIDE_ / nc;
  const int lpc = 16 - (31 - __builtin_clz(nc));  // log2(Pc)
  const int Tc  = T_ / nc;
  const int ltc = lpc - 9;                         // log2(Tc)

  char* ws = (char*)d_ws;
  size_t off = 0;
  auto carve = [&](size_t bytes) -> char* {
    char* p = ws + off;
    off += (bytes + 255) & ~(size_t)255;
    return p;
  };
  unsigned short* wlp      = (unsigned short*)carve((size_t)C_ * C_ * 2);
  unsigned short* wqin     = (unsigned short*)carve((size_t)2 * C_ * C_ * 2);
  unsigned short* wffin    = (unsigned short*)carve((size_t)2 * C_ * C_ * 2);
  unsigned short* wq       = (unsigned short*)carve((size_t)C_ * C_ * 2);
  unsigned short* wk       = (unsigned short*)carve((size_t)C_ * C_ * 2);
  unsigned short* wv       = (unsigned short*)carve((size_t)C_ * C_ * 2);
  unsigned short* wo       = (unsigned short*)carve((size_t)C_ * C_ * 2);
  unsigned short* wqo      = (unsigned short*)carve((size_t)C_ * C_ * 2);
  unsigned short* wfo      = (unsigned short*)carve((size_t)C_ * C_ * 2);
  float*          slat     = (float*)carve((size_t)B_ * PLAT_ * 4);
  unsigned short* latent_h = (unsigned short*)carve((size_t)B_ * C_ * PLAT_ * 2);
  unsigned short* kbuf     = (unsigned short*)carve((size_t)B_ * C_ * PLAT_ * 2);
  unsigned short* vbuf     = (unsigned short*)carve((size_t)B_ * C_ * PLAT_ * 2);
  float*          srow     = (float*)carve((size_t)B_ * Pc * 4);
  unsigned short* big0     = (unsigned short*)carve((size_t)B_ * C_ * Pc * 2);
  float* qh = out;   // query_h lives in d_out until o-gemm RMWs it (same index)

  const dim3 blk(256);
  const dim3 gLat(PLAT_ / 128, C_ / 64, B_);
  const dim3 gCh(Pc / 128, C_ / 64, B_);
  const int NW = C_ * C_;   // 65536

  // weight prep: fold norm weights; convert plain weights to bf16
  wprep_k<<<dim3(NW / 256), blk, 0, stream>>>(lp_w, lp_norm_w, wlp, NW);
  wprep_k<<<dim3(2 * NW / 256), blk, 0, stream>>>(qmlp_in_w, qn_w, wqin, 2 * NW);
  wprep_k<<<dim3(2 * NW / 256), blk, 0, stream>>>(ffn_in_w, ffn_norm_w, wffin, 2 * NW);
  cvt_k<<<dim3(NW / 256), blk, 0, stream>>>(q_w, wq, NW);
  cvt_k<<<dim3(NW / 256), blk, 0, stream>>>(k_w, wk, NW);
  cvt_k<<<dim3(NW / 256), blk, 0, stream>>>(v_w, wv, NW);
  cvt_k<<<dim3(NW / 256), blk, 0, stream>>>(o_w, wo, NW);
  cvt_k<<<dim3(NW / 256), blk, 0, stream>>>(qmlp_out_w, wqo, NW);
  cvt_k<<<dim3(NW / 256), blk, 0, stream>>>(ffn_out_w, wfo, NW);

  // latent path (once)
  rms_k<<<dim3(B_ * PLAT_ / 64), blk, 0, stream>>>(latent, slat, PLAT_, 0, 13);
  gemm_k<EPI_SILU, float, unsigned short><<<gLat, blk, 0, stream>>>(
      latent, wlp, lp_b, slat, nullptr, latent_h, PLAT_, 0, PLAT_, 0, PLAT_);
  gemm_k<EPI_NONE, unsigned short, unsigned short><<<gLat, blk, 0, stream>>>(
      latent_h, wk, k_b, nullptr, nullptr, kbuf, PLAT_, 0, PLAT_, 0, PLAT_);
  gemm_k<EPI_NONE, unsigned short, unsigned short><<<gLat, blk, 0, stream>>>(
      latent_h, wv, v_b, nullptr, nullptr, vbuf, PLAT_, 0, PLAT_, 0, PLAT_);

  // side path, chunked over t
  for (int ch = 0; ch < nc; ++ch) {
    const int co = ch * Pc;
    const int t0 = ch * Tc;
    rms_k<<<dim3(B_ * Pc / 64), blk, 0, stream>>>(side, srow, PSIDE_, co, lpc);
    // big0 = swiglu(qmlp_in @ rms(side))
    gemm_k<EPI_SWIGLU, float, unsigned short><<<gCh, blk, 0, stream>>>(
        side, wqin, qmlp_in_b, srow, nullptr, big0, PSIDE_, co, Pc, 0, Pc);
    // qh = qmlp_out @ big0   (fp32, lives in d_out)
    gemm_k<EPI_NONE, unsigned short, float><<<gCh, blk, 0, stream>>>(
        big0, wqo, qmlp_out_b, nullptr, nullptr, qh, Pc, 0, PSIDE_, co, Pc);
    // big0 = q_w @ qh
    gemm_k<EPI_NONE, float, unsigned short><<<gCh, blk, 0, stream>>>(
        qh, wq, q_b, nullptr, nullptr, big0, PSIDE_, co, Pc, 0, Pc);
    // attention in-place over big0
    attn_k<<<dim3(B_ * Tc), blk, 0, stream>>>(big0, kbuf, vbuf, basis, sc_scale, pr_scale,
                                              big0, Pc, t0, ltc);
    // out = o_w @ attended + o_b + qss*qh  (aliases qh: same-index RMW)
    gemm_k<EPI_SKIP, unsigned short, float><<<gCh, blk, 0, stream>>>(
        big0, wo, o_b, nullptr, qk_scale, out, Pc, 0, PSIDE_, co, Pc);
    // FFN
    rms_k<<<dim3(B_ * Pc / 64), blk, 0, stream>>>(out, srow, PSIDE_, co, lpc);
    gemm_k<EPI_SWIGLU, float, unsigned short><<<gCh, blk, 0, stream>>>(
        out, wffin, ffn_in_b, srow, nullptr, big0, PSIDE_, co, Pc, 0, Pc);
    gemm_k<EPI_RESID, unsigned short, float><<<gCh, blk, 0, stream>>>(
        big0, wfo, ffn_out_b, nullptr, nullptr, out, Pc, 0, PSIDE_, co, Pc);
  }
}